// Round 2
// baseline (296.706 us; speedup 1.0000x reference)
//
#include <hip/hip_runtime.h>
#include <math.h>

#define B_ 16
#define H_ 8
#define D_ 128
#define BS_ 16
#define BPS_ 128
#define T_ (BPS_ * BS_)       // 2048 tokens per sequence
#define ROW_ (H_ * D_)        // 1024 floats = 4 KiB per token row (all heads)
#define SCALE_ 0.08838834764831845f

// Lane mapping (both QK and PV phases):
//   lane l owns head h = l>>3, dim slice d in { i*32 + (l&7)*4 .. +3 }, i=0..3.
// Per-instruction global addresses form 8 contiguous 128B clusters per token row
// (16 cache lines/instr — fully coalesced), and the QK dot reduces over only the
// 8 lanes of a head group via shfl_xor 1/2/4 (all DPP patterns — no DS pipe).
// PV has zero cross-lane traffic: raw scores stay in registers, p recomputed.
template<int NS>
__global__ __launch_bounds__(256, 4) void attn_partial(
    const float* __restrict__ q,
    const float* __restrict__ knew,
    const float* __restrict__ vnew,
    const float* __restrict__ kc,
    const float* __restrict__ vc,
    const int* __restrict__ btab,
    const int* __restrict__ clen,
    float* __restrict__ ws_m,
    float* __restrict__ ws_l,
    float* __restrict__ ws_o)
{
    constexpr int CHUNK = T_ / NS;        // tokens per WG (16 at NS=128)
    constexpr int TPW = CHUNK / 4;        // tokens per wave
    static_assert(TPW % 4 == 0 || TPW == 4, "TPW multiple of 4");
    constexpr int NB = TPW / 4;           // 4-token batches per wave

    const int c = blockIdx.x;
    const int b = blockIdx.y;
    const int tid = threadIdx.x;
    const int wave = tid >> 6;
    const int lane = tid & 63;
    const int h = lane >> 3;              // head owned by this lane
    const int e = (lane & 7) * 4;         // float offset within 32-float segment
    const int ctx = clen[b];
    const int cs = c * CHUNK;
    const int t0 = wave * TPW;

    __shared__ float s_p[H_][CHUNK + 1];  // raw scores (stats phase only); +1 pad
    __shared__ float s_mx[H_], s_l[H_];
    __shared__ float s_o[4][H_ * D_];     // per-wave PV partials (16 KiB)

    // Q fragment: head h, dims {i*32+e .. +3}
    float4 q4[4];
    #pragma unroll
    for (int i = 0; i < 4; ++i)
        q4[i] = *(const float4*)(q + (size_t)b * ROW_ + h * 128 + i * 32 + e);

    float sc[TPW];                        // raw scaled scores, kept in registers

    // ---- QK: per 4-token batch, 16 loads in one burst, then consume ----
    #pragma unroll
    for (int bt = 0; bt < NB; ++bt) {
        float4 kb[4][4];
        #pragma unroll
        for (int u = 0; u < 4; ++u) {
            const int t = t0 + bt * 4 + u;
            const int tg = cs + t;
            const int blk = btab[b * BPS_ + (tg >> 4)];      // wave-uniform
            const float* rb = (tg == ctx - 1)
                ? (knew + (size_t)b * ROW_)
                : (kc + ((size_t)blk * BS_ + (t & 15)) * ROW_);
            #pragma unroll
            for (int i = 0; i < 4; ++i)
                kb[u][i] = *(const float4*)(rb + h * 128 + i * 32 + e);
        }
        #pragma unroll
        for (int u = 0; u < 4; ++u) {
            const int t = t0 + bt * 4 + u;
            const int tg = cs + t;
            float s = 0.f;
            #pragma unroll
            for (int i = 0; i < 4; ++i)
                s += q4[i].x * kb[u][i].x + q4[i].y * kb[u][i].y
                   + q4[i].z * kb[u][i].z + q4[i].w * kb[u][i].w;
            s += __shfl_xor(s, 1);        // DPP quad_perm
            s += __shfl_xor(s, 2);        // DPP quad_perm
            s += __shfl_xor(s, 4);        // DPP row_half_mirror
            s = (tg < ctx) ? s * SCALE_ : -INFINITY;
            sc[bt * 4 + u] = s;           // every lane of the group holds it
            if ((lane & 7) == 0) s_p[h][t] = s;
        }
    }

    // ---- prefetch V batch 0 BEFORE the stats barriers (loads stay in flight) --
    float4 vb0[4][4];
    #pragma unroll
    for (int u = 0; u < 4; ++u) {
        const int t = t0 + u;
        const int tg = cs + t;
        const int blk = btab[b * BPS_ + (tg >> 4)];
        const float* rb = (tg == ctx - 1)
            ? (vnew + (size_t)b * ROW_)
            : (vc + ((size_t)blk * BS_ + (t & 15)) * ROW_);
        #pragma unroll
        for (int i = 0; i < 4; ++i)
            vb0[u][i] = *(const float4*)(rb + h * 128 + i * 32 + e);
    }

    // barrier that drains LDS only — NOT vmcnt (keeps V loads in flight)
    asm volatile("s_waitcnt lgkmcnt(0)" ::: "memory");
    __builtin_amdgcn_s_barrier();
    __builtin_amdgcn_sched_barrier(0);

    // ---- per-head softmax stats over the chunk (32-lane group per head) ----
    {
        const int hh = tid >> 5;
        const int j = tid & 31;
        float m = -INFINITY;
        for (int t = j; t < CHUNK; t += 32) m = fmaxf(m, s_p[hh][t]);
        m = fmaxf(m, __shfl_xor(m, 16));
        m = fmaxf(m, __shfl_xor(m, 8));
        m = fmaxf(m, __shfl_xor(m, 4));
        m = fmaxf(m, __shfl_xor(m, 2));
        m = fmaxf(m, __shfl_xor(m, 1));
        m = fmaxf(m, -1e30f);
        float l = 0.f;
        for (int t = j; t < CHUNK; t += 32) l += __expf(s_p[hh][t] - m);
        l += __shfl_xor(l, 16);
        l += __shfl_xor(l, 8);
        l += __shfl_xor(l, 4);
        l += __shfl_xor(l, 2);
        l += __shfl_xor(l, 1);
        if (j == 0) { s_mx[hh] = m; s_l[hh] = l; }
    }

    asm volatile("s_waitcnt lgkmcnt(0)" ::: "memory");
    __builtin_amdgcn_s_barrier();
    __builtin_amdgcn_sched_barrier(0);

    const float mx = s_mx[h];             // LDS broadcast, once

    // ---- PV: recompute p from registers; zero cross-lane ops ----
    float4 acc[4];
    #pragma unroll
    for (int i = 0; i < 4; ++i) acc[i] = make_float4(0.f, 0.f, 0.f, 0.f);

    #pragma unroll
    for (int u = 0; u < 4; ++u) {
        const float pw = __expf(sc[u] - mx);
        #pragma unroll
        for (int i = 0; i < 4; ++i) {
            acc[i].x += pw * vb0[u][i].x;
            acc[i].y += pw * vb0[u][i].y;
            acc[i].z += pw * vb0[u][i].z;
            acc[i].w += pw * vb0[u][i].w;
        }
    }
    // remaining batches (only for fallback NS<128 paths)
    #pragma unroll
    for (int bt = 1; bt < NB; ++bt) {
        float4 vb[4][4];
        #pragma unroll
        for (int u = 0; u < 4; ++u) {
            const int t = t0 + bt * 4 + u;
            const int tg = cs + t;
            const int blk = btab[b * BPS_ + (tg >> 4)];
            const float* rb = (tg == ctx - 1)
                ? (vnew + (size_t)b * ROW_)
                : (vc + ((size_t)blk * BS_ + (t & 15)) * ROW_);
            #pragma unroll
            for (int i = 0; i < 4; ++i)
                vb[u][i] = *(const float4*)(rb + h * 128 + i * 32 + e);
        }
        #pragma unroll
        for (int u = 0; u < 4; ++u) {
            const float pw = __expf(sc[bt * 4 + u] - mx);
            #pragma unroll
            for (int i = 0; i < 4; ++i) {
                acc[i].x += pw * vb[u][i].x;
                acc[i].y += pw * vb[u][i].y;
                acc[i].z += pw * vb[u][i].z;
                acc[i].w += pw * vb[u][i].w;
            }
        }
    }

    #pragma unroll
    for (int i = 0; i < 4; ++i)
        *(float4*)&s_o[wave][h * 128 + i * 32 + e] = acc[i];

    asm volatile("s_waitcnt lgkmcnt(0)" ::: "memory");
    __builtin_amdgcn_s_barrier();
    __builtin_amdgcn_sched_barrier(0);

    // ---- combine 4 waves, write chunk partials ----
    for (int r = tid; r < H_ * D_; r += 256) {
        const float oo = s_o[0][r] + s_o[1][r] + s_o[2][r] + s_o[3][r];
        ws_o[((size_t)(b * H_ + (r >> 7)) * NS + c) * D_ + (r & 127)] = oo;
    }
    if (tid < H_) {
        ws_m[(b * H_ + tid) * NS + c] = s_mx[tid];
        ws_l[(b * H_ + tid) * NS + c] = s_l[tid];
    }
}

// Kernel 2: combine NS chunk partials per (b,h) with online-softmax rescale.
template<int NS>
__global__ __launch_bounds__(128) void attn_reduce(
    const float* __restrict__ ws_m,
    const float* __restrict__ ws_l,
    const float* __restrict__ ws_o,
    float* __restrict__ out)
{
    const int bh = blockIdx.x;    // 0..127
    const int tid = threadIdx.x;  // 0..127 = d

    __shared__ float s_co[NS];
    __shared__ float s_lg;

    if (tid < 64) {
        float m = -INFINITY;
        for (int cc = tid; cc < NS; cc += 64) m = fmaxf(m, ws_m[bh * NS + cc]);
        m = fmaxf(m, __shfl_xor(m, 32));
        m = fmaxf(m, __shfl_xor(m, 16));
        m = fmaxf(m, __shfl_xor(m, 8));
        m = fmaxf(m, __shfl_xor(m, 4));
        m = fmaxf(m, __shfl_xor(m, 2));
        m = fmaxf(m, __shfl_xor(m, 1));   // m = global max, all lanes
        float lw = 0.f;
        for (int cc = tid; cc < NS; cc += 64) {
            const float co = __expf(ws_m[bh * NS + cc] - m);
            s_co[cc] = co;
            lw += ws_l[bh * NS + cc] * co;
        }
        lw += __shfl_xor(lw, 32);
        lw += __shfl_xor(lw, 16);
        lw += __shfl_xor(lw, 8);
        lw += __shfl_xor(lw, 4);
        lw += __shfl_xor(lw, 2);
        lw += __shfl_xor(lw, 1);
        if (tid == 0) s_lg = lw;
    }
    __syncthreads();

    float acc = 0.f;
    #pragma unroll 8
    for (int cc = 0; cc < NS; ++cc)
        acc += s_co[cc] * ws_o[((size_t)bh * NS + cc) * D_ + tid];
    out[(size_t)bh * D_ + tid] = acc / s_lg;
}

template<int NS>
static void launch_all(const float* q, const float* knew, const float* vnew,
                       const float* kc, const float* vc,
                       const int* btab, const int* clen,
                       float* ws, float* out, hipStream_t stream)
{
    float* ws_m = ws;
    float* ws_l = ws + B_ * H_ * NS;
    float* ws_o = ws + 2 * B_ * H_ * NS;
    attn_partial<NS><<<dim3(NS, B_), 256, 0, stream>>>(q, knew, vnew, kc, vc,
                                                       btab, clen, ws_m, ws_l, ws_o);
    attn_reduce<NS><<<dim3(B_ * H_), 128, 0, stream>>>(ws_m, ws_l, ws_o, out);
}

extern "C" void kernel_launch(void* const* d_in, const int* in_sizes, int n_in,
                              void* d_out, int out_size, void* d_ws, size_t ws_size,
                              hipStream_t stream) {
    const float* q    = (const float*)d_in[0];
    const float* knew = (const float*)d_in[1];
    const float* vnew = (const float*)d_in[2];
    const float* kc   = (const float*)d_in[3];
    const float* vc   = (const float*)d_in[4];
    // d_in[5] = slot_mapping: unused — slot == position of token ctx-1 in the
    // batch's own block-table row (rows disjoint), handled by in-flight substitution.
    const int* btab = (const int*)d_in[6];
    const int* clen = (const int*)d_in[7];
    float* out = (float*)d_out;
    float* ws  = (float*)d_ws;

    // scratch need for split NS: B*H*NS*(2 + D) floats
    const size_t need128 = (size_t)B_ * H_ * 128 * (2 + D_) * sizeof(float); // ~8.5 MiB
    const size_t need64  = (size_t)B_ * H_ * 64  * (2 + D_) * sizeof(float); // ~4.3 MiB
    const size_t need32  = (size_t)B_ * H_ * 32  * (2 + D_) * sizeof(float);
    if (ws_size >= need128)     launch_all<128>(q, knew, vnew, kc, vc, btab, clen, ws, out, stream);
    else if (ws_size >= need64) launch_all<64>(q, knew, vnew, kc, vc, btab, clen, ws, out, stream);
    else if (ws_size >= need32) launch_all<32>(q, knew, vnew, kc, vc, btab, clen, ws, out, stream);
    else                        launch_all<16>(q, knew, vnew, kc, vc, btab, clen, ws, out, stream);
}